// Round 14
// baseline (479.021 us; speedup 1.0000x reference)
//
#include <hip/hip_runtime.h>
#include <math.h>

#define B_     16
#define C_     64
#define HW_    512
#define KS_    15
#define HALO   7
#define PROW   528      // padded row: 8 + 512 + 8 floats (16B-aligned)
#define PADOFF 2048     // float offset of padded image inside ws (8 KB coefs)
#define YSEG   128      // rows per wave
#define NSEG   4        // 512 / YSEG
#define NPH    3        // unroll phases per group (17 slots -> fits 102 VGPR)

typedef float vf4 __attribute__((ext_vector_type(4)));

// ---------------------------------------------------------------------------
// coefs[c*32 + i]      = F2*sinc(pi*F2*(i-7))*hamming[i]   (A)
// coefs[c*32 + 16 + i] = F1*sinc(pi*F1*(i-7))*hamming[i]   (B)
// Palindromic (cf[k]==cf[14-k], R10-proven); conv kernel reads k=0..7 only.
// ---------------------------------------------------------------------------
__global__ void make_filters(const float* __restrict__ f1,
                             const float* __restrict__ band,
                             float* __restrict__ coefs) {
    int c = threadIdx.x;
    if (c >= C_) return;
    float F1 = f1[c];
    float F2 = F1 + fabsf(band[c]);
    const float PI = 3.14159265358979323846f;
    #pragma unroll
    for (int i = 0; i < KS_; ++i) {
        float h = 0.54f - 0.46f * cosf((2.0f * PI / 14.0f) * (float)i);
        float y1, y2;
        if (i == HALO) {
            y1 = 1.0f; y2 = 1.0f;
        } else {
            float t  = (float)(i - HALO);
            float a1 = PI * F1 * t;
            float a2 = PI * F2 * t;
            y1 = sinf(a1) / a1;
            y2 = sinf(a2) / a2;
        }
        coefs[c * 32 + i]      = F2 * y2 * h;
        coefs[c * 32 + 16 + i] = F1 * y1 * h;
    }
}

// ---------------------------------------------------------------------------
// Column-padded input copy (R5/R8-proven): xp[row*528 + gx + 8] = x[row*512+gx]
// ---------------------------------------------------------------------------
__global__ void pad_copy(const float* __restrict__ x, float* __restrict__ xp) {
    int t   = blockIdx.x * 256 + threadIdx.x;   // 8192 rows * 132 quads
    int pc4 = t % 132;
    int row = t / 132;
    const float* src = x + (size_t)row * HW_;
    int gx0 = pc4 * 4 - 8;
    float v[4];
    #pragma unroll
    for (int e = 0; e < 4; ++e) {
        int gx = gx0 + e;
        v[e] = ((unsigned)gx < (unsigned)HW_) ? src[gx] : 0.0f;
    }
    *(vf4*)(xp + (size_t)row * PROW + pc4 * 4) = *(const vf4*)v;
}

// ---------------------------------------------------------------------------
// Fused single-pass separable conv, 4 cols/thread, no LDS.
// Body identical to R11 (proven). Occupancy changes only:
//   - 128-thread blocks: 2 waves/block (the two xh halves) -> the 16-wg/CU
//     cap allows up to 32 waves/CU instead of 16.
//   - YSEG=128/NSEG=4: 8192 total waves = 32/CU available.
//   - __launch_bounds__(128,5): cap VGPR at ~102 -> 5 waves/SIMD resident.
// Phase u (0..2), input row y = y0-7+r, r = 3g+u:
//   tap j=0..13: phys slot u+j += cf[14-j]*h   (static indices)
//   tap j=14:    phys slot u+14 = MUL-init with cf[0] (row restart)
//   store phys slot u -> output row y-7 (guarded to [y0, y0+YSEG))
// Group end: shift acc[p] = acc[p+3], p=0..13.
// OOB rows run with w=0 (MUL-init still executes -> correct restart).
// 144 iterations (48 groups of 3); r>141 iterations are store-guarded off.
// ---------------------------------------------------------------------------
__global__ __launch_bounds__(128, 5)
void sinc_u3w2(const float* __restrict__ xpad,
               const float* __restrict__ coefs,
               float* __restrict__ out) {
    const int tid  = threadIdx.x;
    const int lane = tid & 63;
    const int xh   = tid >> 6;                 // wave id in block = column half
    const int bid  = blockIdx.x;
    const int ch   = bid & 63;                 // channel fastest (L2 sharing)
    const int seg  = (bid >> 6) & (NSEG - 1);
    const int b    = bid >> 8;
    const int sx   = xh * 256;
    const int y0   = seg * YSEG;
    const int c0   = sx + 4 * lane;

    // wave-uniform half-coefficients -> SGPR (palindrome: cf[k]=cf[14-k])
    float cA[8], cB[8];
    #pragma unroll
    for (int i = 0; i < 8; ++i) {
        cA[i] = __uint_as_float(__builtin_amdgcn_readfirstlane(
                    __float_as_uint(coefs[ch * 32 + i])));
        cB[i] = __uint_as_float(__builtin_amdgcn_readfirstlane(
                    __float_as_uint(coefs[ch * 32 + 16 + i])));
    }

    const float* xw = xpad + (size_t)b * HW_ * PROW + c0;  // + y*PROW per row
    float* ob = out + ((size_t)(b * C_ + ch) * HW_) * HW_ + c0;

    float acc[NPH + 14][4];                    // 17 slots
    #pragma unroll
    for (int j = 0; j < NPH + 14; ++j)
        #pragma unroll
        for (int c = 0; c < 4; ++c) acc[j][c] = 0.0f;

    #pragma unroll 1
    for (int g = 0; g < 48; ++g) {
        #pragma unroll
        for (int u = 0; u < NPH; ++u) {
            const int r = g * NPH + u;         // iteration index 0..143
            const int y = y0 - HALO + r;       // input row

            // load 20-float window (5x aligned dwordx4), zero when OOB
            float w[20] __attribute__((aligned(16)));
            if ((unsigned)y < (unsigned)HW_) {
                const float* p = xw + (size_t)y * PROW;
                #pragma unroll
                for (int m = 0; m < 5; ++m)
                    *(vf4*)(w + 4 * m) = *(const vf4*)(p + 4 * m);
            } else {
                #pragma unroll
                for (int m = 0; m < 20; ++m) w[m] = 0.0f;
            }

            // symmetric hconv: h(c0+c) = cf[7]*w[c+8] + sum cf[k]*(w+w)
            float hA[4], hB[4];
            #pragma unroll
            for (int c = 0; c < 4; ++c) {
                hA[c] = cA[7] * w[c + 8];
                hB[c] = cB[7] * w[c + 8];
            }
            #pragma unroll
            for (int k = 0; k < 7; ++k) {
                #pragma unroll
                for (int c = 0; c < 4; ++c) {
                    float s = w[c + k + 1] + w[c + 15 - k];
                    hA[c] = fmaf(cA[k], s, hA[c]);
                    hB[c] = fmaf(cB[k], s, hB[c]);
                }
            }

            // tap j=14: MUL-init phys slot u+14 (row y+7 restart, cf[0])
            #pragma unroll
            for (int c = 0; c < 4; ++c)
                acc[u + 14][c] = fmaf(-cB[0], hB[c], cA[0] * hA[c]);
            // taps j=0..13: phys slot u+j += cf[14-j]*h (palindrome index)
            #pragma unroll
            for (int j = 0; j < 14; ++j) {
                const int m  = 14 - j;
                const int ci = (m < 8) ? m : 14 - m;
                #pragma unroll
                for (int c = 0; c < 4; ++c) {
                    acc[u + j][c] = fmaf( cA[ci], hA[c], acc[u + j][c]);
                    acc[u + j][c] = fmaf(-cB[ci], hB[c], acc[u + j][c]);
                }
            }
            // store completed output row yo = y-7 from phys slot u
            const int rel = r - 14;
            if ((unsigned)rel < (unsigned)YSEG) {
                vf4 st = {acc[u][0], acc[u][1], acc[u][2], acc[u][3]};
                __builtin_nontemporal_store(st,
                    (vf4*)(ob + (size_t)(y0 + rel) * HW_));
            }
        }
        // shift delay line by NPH (14 live slots, 56 movs per 3 rows)
        #pragma unroll
        for (int p = 0; p < 14; ++p)
            #pragma unroll
            for (int c = 0; c < 4; ++c)
                acc[p][c] = acc[p + NPH][c];
    }
}

extern "C" void kernel_launch(void* const* d_in, const int* in_sizes, int n_in,
                              void* d_out, int out_size, void* d_ws, size_t ws_size,
                              hipStream_t stream) {
    const float* x    = (const float*)d_in[0];
    const float* f1   = (const float*)d_in[1];
    const float* band = (const float*)d_in[2];
    float* ws   = (float*)d_ws;
    float* outp = (float*)d_out;
    float* xp   = ws + PADOFF;

    hipLaunchKernelGGL(make_filters, dim3(1), dim3(64), 0, stream,
                       f1, band, ws);
    hipLaunchKernelGGL(pad_copy, dim3(4224), dim3(256), 0, stream, x, xp);

    const int nblocks = B_ * C_ * NSEG;        // 4096 blocks x 2 waves
    hipLaunchKernelGGL(sinc_u3w2, dim3(nblocks), dim3(128), 0, stream,
                       xp, ws, outp);
}

// Round 15
// 458.014 us; speedup vs baseline: 1.0459x; 1.0459x over previous
//
#include <hip/hip_runtime.h>
#include <math.h>

#define B_     16
#define C_     64
#define HW_    512
#define KS_    15
#define HALO   7
#define PROW   528      // padded row: 8 + 512 + 8 floats (16B-aligned)
#define PADOFF 2048     // float offset of padded image inside ws (8 KB coefs)
#define YSEG   128      // rows per wave
#define NSEG   4        // 512 / YSEG
#define NPH    3        // slot phases (17-slot delay line, R11-proven)

typedef float vf4 __attribute__((ext_vector_type(4)));

// ---------------------------------------------------------------------------
// coefs[c*32 + i]      = F2*sinc(pi*F2*(i-7))*hamming[i]   (A)
// coefs[c*32 + 16 + i] = F1*sinc(pi*F1*(i-7))*hamming[i]   (B)
// Palindromic (cf[k]==cf[14-k], R10-proven); conv kernel reads k=0..7 only.
// ---------------------------------------------------------------------------
__global__ void make_filters(const float* __restrict__ f1,
                             const float* __restrict__ band,
                             float* __restrict__ coefs) {
    int c = threadIdx.x;
    if (c >= C_) return;
    float F1 = f1[c];
    float F2 = F1 + fabsf(band[c]);
    const float PI = 3.14159265358979323846f;
    #pragma unroll
    for (int i = 0; i < KS_; ++i) {
        float h = 0.54f - 0.46f * cosf((2.0f * PI / 14.0f) * (float)i);
        float y1, y2;
        if (i == HALO) {
            y1 = 1.0f; y2 = 1.0f;
        } else {
            float t  = (float)(i - HALO);
            float a1 = PI * F1 * t;
            float a2 = PI * F2 * t;
            y1 = sinf(a1) / a1;
            y2 = sinf(a2) / a2;
        }
        coefs[c * 32 + i]      = F2 * y2 * h;
        coefs[c * 32 + 16 + i] = F1 * y1 * h;
    }
}

// ---------------------------------------------------------------------------
// Column-padded input copy (R5/R8-proven): xp[row*528 + gx + 8] = x[row*512+gx]
// ---------------------------------------------------------------------------
__global__ void pad_copy(const float* __restrict__ x, float* __restrict__ xp) {
    int t   = blockIdx.x * 256 + threadIdx.x;   // 8192 rows * 132 quads
    int pc4 = t % 132;
    int row = t / 132;
    const float* src = x + (size_t)row * HW_;
    int gx0 = pc4 * 4 - 8;
    float v[4];
    #pragma unroll
    for (int e = 0; e < 4; ++e) {
        int gx = gx0 + e;
        v[e] = ((unsigned)gx < (unsigned)HW_) ? src[gx] : 0.0f;
    }
    *(vf4*)(xp + (size_t)row * PROW + pc4 * 4) = *(const vf4*)v;
}

// ---------------------------------------------------------------------------
// Fused single-pass separable conv, 4 cols/thread, no LDS, STATIC 2-BUFFER
// SOFTWARE PIPELINE. Body algebra identical to proven R11/R13:
//   17-slot delay line, 3-phase static slot indexing, symmetric hconv,
//   MUL-init tap (cf[0]) as row restart, guarded store of slot u%3.
// New: two statically-named window buffers wA/wB. Each iteration issues the
// OTHER buffer's 5 dwordx4 loads (row y+1) BEFORE consuming the current
// buffer -> each load has a full compute phase (~480 cyc) of slack and the
// compiler emits a counted vmcnt instead of a drain. Slot phase (mod 3) x
// buffer parity (mod 2) -> 6-row static unroll, 24 groups.
// OOB rows are zero-filled (MUL-init still executes -> correct restart).
// ---------------------------------------------------------------------------
__global__ __launch_bounds__(64, 4)
void sinc_db(const float* __restrict__ xpad,
             const float* __restrict__ coefs,
             float* __restrict__ out) {
    const int lane = threadIdx.x;              // 64 threads = 1 wave
    const int bid  = blockIdx.x;
    const int ch   = bid & 63;                 // channel fastest (L2 sharing)
    const int xh   = (bid >> 6) & 1;
    const int seg  = (bid >> 7) & (NSEG - 1);
    const int b    = bid >> 9;
    const int sx   = xh * 256;
    const int y0   = seg * YSEG;
    const int c0   = sx + 4 * lane;

    // wave-uniform half-coefficients -> SGPR (palindrome: cf[k]=cf[14-k])
    float cA[8], cB[8];
    #pragma unroll
    for (int i = 0; i < 8; ++i) {
        cA[i] = __uint_as_float(__builtin_amdgcn_readfirstlane(
                    __float_as_uint(coefs[ch * 32 + i])));
        cB[i] = __uint_as_float(__builtin_amdgcn_readfirstlane(
                    __float_as_uint(coefs[ch * 32 + 16 + i])));
    }

    const float* xw = xpad + (size_t)b * HW_ * PROW + c0;  // + y*PROW per row
    float* ob = out + ((size_t)(b * C_ + ch) * HW_) * HW_ + c0;

    float acc[NPH + 14][4];                    // 17 slots
    #pragma unroll
    for (int j = 0; j < NPH + 14; ++j)
        #pragma unroll
        for (int c = 0; c < 4; ++c) acc[j][c] = 0.0f;

    float wA[20] __attribute__((aligned(16)));
    float wB[20] __attribute__((aligned(16)));

#define LOADW(W, Y)                                                          \
    {                                                                        \
        const int y_ = (Y);                                                  \
        if ((unsigned)y_ < (unsigned)HW_) {                                  \
            const float* p_ = xw + (size_t)y_ * PROW;                        \
            _Pragma("unroll")                                                \
            for (int m_ = 0; m_ < 5; ++m_)                                   \
                *(vf4*)((W) + 4 * m_) = *(const vf4*)(p_ + 4 * m_);          \
        } else {                                                             \
            _Pragma("unroll")                                                \
            for (int m_ = 0; m_ < 20; ++m_) (W)[m_] = 0.0f;                  \
        }                                                                    \
    }

#define PHASE(U3, W, R)                                                      \
    {                                                                        \
        float hA_[4], hB_[4];                                                \
        _Pragma("unroll")                                                    \
        for (int c_ = 0; c_ < 4; ++c_) {                                     \
            hA_[c_] = cA[7] * (W)[c_ + 8];                                   \
            hB_[c_] = cB[7] * (W)[c_ + 8];                                   \
        }                                                                    \
        _Pragma("unroll")                                                    \
        for (int k_ = 0; k_ < 7; ++k_) {                                     \
            _Pragma("unroll")                                                \
            for (int c_ = 0; c_ < 4; ++c_) {                                 \
                float s_ = (W)[c_ + k_ + 1] + (W)[c_ + 15 - k_];             \
                hA_[c_] = fmaf(cA[k_], s_, hA_[c_]);                         \
                hB_[c_] = fmaf(cB[k_], s_, hB_[c_]);                         \
            }                                                                \
        }                                                                    \
        _Pragma("unroll")                                                    \
        for (int c_ = 0; c_ < 4; ++c_)                                       \
            acc[(U3) + 14][c_] = fmaf(-cB[0], hB_[c_], cA[0] * hA_[c_]);     \
        _Pragma("unroll")                                                    \
        for (int j_ = 0; j_ < 14; ++j_) {                                    \
            const int m_  = 14 - j_;                                         \
            const int ci_ = (m_ < 8) ? m_ : 14 - m_;                         \
            _Pragma("unroll")                                                \
            for (int c_ = 0; c_ < 4; ++c_) {                                 \
                acc[(U3) + j_][c_] =                                         \
                    fmaf( cA[ci_], hA_[c_], acc[(U3) + j_][c_]);             \
                acc[(U3) + j_][c_] =                                         \
                    fmaf(-cB[ci_], hB_[c_], acc[(U3) + j_][c_]);             \
            }                                                                \
        }                                                                    \
        const int rel_ = (R) - 14;                                           \
        if ((unsigned)rel_ < (unsigned)YSEG) {                               \
            vf4 st_ = {acc[(U3)][0], acc[(U3)][1],                           \
                       acc[(U3)][2], acc[(U3)][3]};                          \
            __builtin_nontemporal_store(st_,                                 \
                (vf4*)(ob + (size_t)(y0 + rel_) * HW_));                     \
        }                                                                    \
    }

#define SHIFT3()                                                             \
    {                                                                        \
        _Pragma("unroll")                                                    \
        for (int p_ = 0; p_ < 14; ++p_)                                      \
            _Pragma("unroll")                                                \
            for (int c_ = 0; c_ < 4; ++c_)                                   \
                acc[p_][c_] = acc[p_ + NPH][c_];                             \
    }

    LOADW(wA, y0 - HALO);                      // prologue: row r=0 into wA

    #pragma unroll 1
    for (int g = 0; g < 24; ++g) {             // 24 groups x 6 rows = 144
        const int r0 = g * 6;
        const int yb = y0 - HALO + r0;         // row consumed at u=0 (in wA)
        LOADW(wB, yb + 1);  PHASE(0, wA, r0 + 0);
        LOADW(wA, yb + 2);  PHASE(1, wB, r0 + 1);
        LOADW(wB, yb + 3);  PHASE(2, wA, r0 + 2);
        SHIFT3();
        LOADW(wA, yb + 4);  PHASE(0, wB, r0 + 3);
        LOADW(wB, yb + 5);  PHASE(1, wA, r0 + 4);
        LOADW(wA, yb + 6);  PHASE(2, wB, r0 + 5);
        SHIFT3();
    }
#undef LOADW
#undef PHASE
#undef SHIFT3
}

extern "C" void kernel_launch(void* const* d_in, const int* in_sizes, int n_in,
                              void* d_out, int out_size, void* d_ws, size_t ws_size,
                              hipStream_t stream) {
    const float* x    = (const float*)d_in[0];
    const float* f1   = (const float*)d_in[1];
    const float* band = (const float*)d_in[2];
    float* ws   = (float*)d_ws;
    float* outp = (float*)d_out;
    float* xp   = ws + PADOFF;

    hipLaunchKernelGGL(make_filters, dim3(1), dim3(64), 0, stream,
                       f1, band, ws);
    hipLaunchKernelGGL(pad_copy, dim3(4224), dim3(256), 0, stream, x, xp);

    const int nblocks = B_ * C_ * 2 * NSEG;    // 8192 one-wave blocks
    hipLaunchKernelGGL(sinc_db, dim3(nblocks), dim3(64), 0, stream,
                       xp, ws, outp);
}

// Round 16
// 441.652 us; speedup vs baseline: 1.0846x; 1.0370x over previous
//
#include <hip/hip_runtime.h>
#include <math.h>

#define B_     16
#define C_     64
#define HW_    512
#define KS_    15
#define HALO   7
#define PROW   528      // padded row: 8 + 512 + 8 floats (16B-aligned)
#define PADOFF 2048     // float offset of padded image inside ws (8 KB coefs)
#define YSEG   128      // rows per wave
#define NSEG   4        // 512 / YSEG
#define NPH    3        // slot phases (17-slot delay line, R11-proven)

typedef float vf4 __attribute__((ext_vector_type(4)));

// ---------------------------------------------------------------------------
// coefs[c*32 + i]      = F2*sinc(pi*F2*(i-7))*hamming[i]   (A)
// coefs[c*32 + 16 + i] = F1*sinc(pi*F1*(i-7))*hamming[i]   (B)
// Palindromic (cf[k]==cf[14-k], R10-proven); conv kernel reads k=0..7 only.
// ---------------------------------------------------------------------------
__global__ void make_filters(const float* __restrict__ f1,
                             const float* __restrict__ band,
                             float* __restrict__ coefs) {
    int c = threadIdx.x;
    if (c >= C_) return;
    float F1 = f1[c];
    float F2 = F1 + fabsf(band[c]);
    const float PI = 3.14159265358979323846f;
    #pragma unroll
    for (int i = 0; i < KS_; ++i) {
        float h = 0.54f - 0.46f * cosf((2.0f * PI / 14.0f) * (float)i);
        float y1, y2;
        if (i == HALO) {
            y1 = 1.0f; y2 = 1.0f;
        } else {
            float t  = (float)(i - HALO);
            float a1 = PI * F1 * t;
            float a2 = PI * F2 * t;
            y1 = sinf(a1) / a1;
            y2 = sinf(a2) / a2;
        }
        coefs[c * 32 + i]      = F2 * y2 * h;
        coefs[c * 32 + 16 + i] = F1 * y1 * h;
    }
}

// ---------------------------------------------------------------------------
// Column-padded input copy (R5/R8-proven): xp[row*528 + gx + 8] = x[row*512+gx]
// ---------------------------------------------------------------------------
__global__ void pad_copy(const float* __restrict__ x, float* __restrict__ xp) {
    int t   = blockIdx.x * 256 + threadIdx.x;   // 8192 rows * 132 quads
    int pc4 = t % 132;
    int row = t / 132;
    const float* src = x + (size_t)row * HW_;
    int gx0 = pc4 * 4 - 8;
    float v[4];
    #pragma unroll
    for (int e = 0; e < 4; ++e) {
        int gx = gx0 + e;
        v[e] = ((unsigned)gx < (unsigned)HW_) ? src[gx] : 0.0f;
    }
    *(vf4*)(xp + (size_t)row * PROW + pc4 * 4) = *(const vf4*)v;
}

// ---------------------------------------------------------------------------
// Fused single-pass separable conv, 4 cols/thread, no LDS, STATIC 2-BUFFER
// SOFTWARE PIPELINE (R15 body) with the two fixes R15 lacked:
//   - __launch_bounds__(64,3): VGPR budget 170 -> no spill/sink pressure
//     (R15's (64,4)=128 budget forced the scheduler to sink the prefetch).
//   - sched_barrier(0) after every LOADW: pins the prefetch ABOVE the
//     consuming PHASE in the emitted code -> loads get a full ~460-cycle
//     compute phase of slack; vmcnt wait is on already-returned data.
// Body algebra identical to proven R11/R13 (17-slot delay line, 3-phase
// static indexing, symmetric hconv, MUL-init restart, guarded stores).
// ---------------------------------------------------------------------------
__global__ __launch_bounds__(64, 3)
void sinc_db3(const float* __restrict__ xpad,
              const float* __restrict__ coefs,
              float* __restrict__ out) {
    const int lane = threadIdx.x;              // 64 threads = 1 wave
    const int bid  = blockIdx.x;
    const int ch   = bid & 63;                 // channel fastest (L2 sharing)
    const int xh   = (bid >> 6) & 1;
    const int seg  = (bid >> 7) & (NSEG - 1);
    const int b    = bid >> 9;
    const int sx   = xh * 256;
    const int y0   = seg * YSEG;
    const int c0   = sx + 4 * lane;

    // wave-uniform half-coefficients -> SGPR (palindrome: cf[k]=cf[14-k])
    float cA[8], cB[8];
    #pragma unroll
    for (int i = 0; i < 8; ++i) {
        cA[i] = __uint_as_float(__builtin_amdgcn_readfirstlane(
                    __float_as_uint(coefs[ch * 32 + i])));
        cB[i] = __uint_as_float(__builtin_amdgcn_readfirstlane(
                    __float_as_uint(coefs[ch * 32 + 16 + i])));
    }

    const float* xw = xpad + (size_t)b * HW_ * PROW + c0;  // + y*PROW per row
    float* ob = out + ((size_t)(b * C_ + ch) * HW_) * HW_ + c0;

    float acc[NPH + 14][4];                    // 17 slots
    #pragma unroll
    for (int j = 0; j < NPH + 14; ++j)
        #pragma unroll
        for (int c = 0; c < 4; ++c) acc[j][c] = 0.0f;

    float wA[20] __attribute__((aligned(16)));
    float wB[20] __attribute__((aligned(16)));

#define LOADW(W, Y)                                                          \
    {                                                                        \
        const int y_ = (Y);                                                  \
        if ((unsigned)y_ < (unsigned)HW_) {                                  \
            const float* p_ = xw + (size_t)y_ * PROW;                        \
            _Pragma("unroll")                                                \
            for (int m_ = 0; m_ < 5; ++m_)                                   \
                *(vf4*)((W) + 4 * m_) = *(const vf4*)(p_ + 4 * m_);          \
        } else {                                                             \
            _Pragma("unroll")                                                \
            for (int m_ = 0; m_ < 20; ++m_) (W)[m_] = 0.0f;                  \
        }                                                                    \
        __builtin_amdgcn_sched_barrier(0);                                   \
    }

#define PHASE(U3, W, R)                                                      \
    {                                                                        \
        float hA_[4], hB_[4];                                                \
        _Pragma("unroll")                                                    \
        for (int c_ = 0; c_ < 4; ++c_) {                                     \
            hA_[c_] = cA[7] * (W)[c_ + 8];                                   \
            hB_[c_] = cB[7] * (W)[c_ + 8];                                   \
        }                                                                    \
        _Pragma("unroll")                                                    \
        for (int k_ = 0; k_ < 7; ++k_) {                                     \
            _Pragma("unroll")                                                \
            for (int c_ = 0; c_ < 4; ++c_) {                                 \
                float s_ = (W)[c_ + k_ + 1] + (W)[c_ + 15 - k_];             \
                hA_[c_] = fmaf(cA[k_], s_, hA_[c_]);                         \
                hB_[c_] = fmaf(cB[k_], s_, hB_[c_]);                         \
            }                                                                \
        }                                                                    \
        _Pragma("unroll")                                                    \
        for (int c_ = 0; c_ < 4; ++c_)                                       \
            acc[(U3) + 14][c_] = fmaf(-cB[0], hB_[c_], cA[0] * hA_[c_]);     \
        _Pragma("unroll")                                                    \
        for (int j_ = 0; j_ < 14; ++j_) {                                    \
            const int m_  = 14 - j_;                                         \
            const int ci_ = (m_ < 8) ? m_ : 14 - m_;                         \
            _Pragma("unroll")                                                \
            for (int c_ = 0; c_ < 4; ++c_) {                                 \
                acc[(U3) + j_][c_] =                                         \
                    fmaf( cA[ci_], hA_[c_], acc[(U3) + j_][c_]);             \
                acc[(U3) + j_][c_] =                                         \
                    fmaf(-cB[ci_], hB_[c_], acc[(U3) + j_][c_]);             \
            }                                                                \
        }                                                                    \
        const int rel_ = (R) - 14;                                           \
        if ((unsigned)rel_ < (unsigned)YSEG) {                               \
            vf4 st_ = {acc[(U3)][0], acc[(U3)][1],                           \
                       acc[(U3)][2], acc[(U3)][3]};                          \
            __builtin_nontemporal_store(st_,                                 \
                (vf4*)(ob + (size_t)(y0 + rel_) * HW_));                     \
        }                                                                    \
    }

#define SHIFT3()                                                             \
    {                                                                        \
        _Pragma("unroll")                                                    \
        for (int p_ = 0; p_ < 14; ++p_)                                      \
            _Pragma("unroll")                                                \
            for (int c_ = 0; c_ < 4; ++c_)                                   \
                acc[p_][c_] = acc[p_ + NPH][c_];                             \
    }

    LOADW(wA, y0 - HALO);                      // prologue: row r=0 into wA

    #pragma unroll 1
    for (int g = 0; g < 24; ++g) {             // 24 groups x 6 rows = 144
        const int r0 = g * 6;
        const int yb = y0 - HALO + r0;         // row consumed at u=0 (in wA)
        LOADW(wB, yb + 1);  PHASE(0, wA, r0 + 0);
        LOADW(wA, yb + 2);  PHASE(1, wB, r0 + 1);
        LOADW(wB, yb + 3);  PHASE(2, wA, r0 + 2);
        SHIFT3();
        LOADW(wA, yb + 4);  PHASE(0, wB, r0 + 3);
        LOADW(wB, yb + 5);  PHASE(1, wA, r0 + 4);
        LOADW(wA, yb + 6);  PHASE(2, wB, r0 + 5);
        SHIFT3();
    }
#undef LOADW
#undef PHASE
#undef SHIFT3
}

extern "C" void kernel_launch(void* const* d_in, const int* in_sizes, int n_in,
                              void* d_out, int out_size, void* d_ws, size_t ws_size,
                              hipStream_t stream) {
    const float* x    = (const float*)d_in[0];
    const float* f1   = (const float*)d_in[1];
    const float* band = (const float*)d_in[2];
    float* ws   = (float*)d_ws;
    float* outp = (float*)d_out;
    float* xp   = ws + PADOFF;

    hipLaunchKernelGGL(make_filters, dim3(1), dim3(64), 0, stream,
                       f1, band, ws);
    hipLaunchKernelGGL(pad_copy, dim3(4224), dim3(256), 0, stream, x, xp);

    const int nblocks = B_ * C_ * 2 * NSEG;    // 8192 one-wave blocks
    hipLaunchKernelGGL(sinc_db3, dim3(nblocks), dim3(64), 0, stream,
                       xp, ws, outp);
}

// Round 17
// 337.620 us; speedup vs baseline: 1.4188x; 1.3081x over previous
//
#include <hip/hip_runtime.h>
#include <math.h>

#define B_     16
#define C_     64
#define HW_    512
#define KS_    15
#define XROW   544      // padded f16 row: col index = x + 7, x in [-7, 537)
#define YROWS  528      // padded rows per batch: row index = y + 7, y in [-7, 521)
#define PADOFF 2048     // floats reserved at ws start for fp32 coefs

typedef _Float16 half8 __attribute__((ext_vector_type(8)));
typedef _Float16 half4 __attribute__((ext_vector_type(4)));
typedef float    f32x4 __attribute__((ext_vector_type(4)));

// ---------------------------------------------------------------------------
// coefs[c*32 + i]      = F2*sinc(pi*F2*(i-7))*hamming[i]   (A)
// coefs[c*32 + 16 + i] = F1*sinc(pi*F1*(i-7))*hamming[i]   (B)
// ---------------------------------------------------------------------------
__global__ void make_filters(const float* __restrict__ f1,
                             const float* __restrict__ band,
                             float* __restrict__ coefs) {
    int c = threadIdx.x;
    if (c >= C_) return;
    float F1 = f1[c];
    float F2 = F1 + fabsf(band[c]);
    const float PI = 3.14159265358979323846f;
    #pragma unroll
    for (int i = 0; i < KS_; ++i) {
        float h = 0.54f - 0.46f * cosf((2.0f * PI / 14.0f) * (float)i);
        float y1, y2;
        if (i == 7) { y1 = 1.0f; y2 = 1.0f; }
        else {
            float t  = (float)(i - 7);
            float a1 = PI * F1 * t;
            float a2 = PI * F2 * t;
            y1 = sinf(a1) / a1;
            y2 = sinf(a2) / a2;
        }
        coefs[c * 32 + i]      = F2 * y2 * h;
        coefs[c * 32 + 16 + i] = F1 * y1 * h;
    }
}

// ---------------------------------------------------------------------------
// Fully padded f16 image: xh[b][y+7][x+7] = (f16)x[b][y][x], zero outside.
// Each thread writes 8 f16 (16 B). Grid exactly covers 16*528*68 groups.
// ---------------------------------------------------------------------------
__global__ void pad_f16(const float* __restrict__ x, _Float16* __restrict__ xh) {
    int t = blockIdx.x * 256 + threadIdx.x;
    if (t >= B_ * YROWS * (XROW / 8)) return;
    int xq = t % (XROW / 8);
    int rr = t / (XROW / 8);
    int yy = rr % YROWS;
    int b  = rr / YROWS;
    int y  = yy - 7;
    half8 v = {0, 0, 0, 0, 0, 0, 0, 0};
    if ((unsigned)y < (unsigned)HW_) {
        const float* src = x + ((size_t)b * HW_ + y) * HW_;
        #pragma unroll
        for (int e = 0; e < 8; ++e) {
            int gx = 8 * xq + e - 7;
            if ((unsigned)gx < (unsigned)HW_) v[e] = (_Float16)src[gx];
        }
    }
    *(half8*)(xh + (size_t)rr * XROW + 8 * xq) = v;
}

// ---------------------------------------------------------------------------
// MFMA separable conv. Both 1-D convs are banded matmuls with the SAME
// 16x32 Toeplitz T[i][k] = cf[k-i] (k-i in [0,14], else 0):
//   stage1: H[i][y]   = sum_k T[i][k] * X[k][y],  X[k][y]=xh[y][c0+k-7]
//   stage2: OUT[y'][x]= sum_k T[i=y'-16t][k] * Hwin[k][x]  (30 of 32 k used)
// y-batches m cover y in [16m-7, 16m+9); tile t consumes batches {t, t+1}.
// A/B fragments use the same (lanegroup,elem)->k map, so any HW k-order is
// correct; C/D layout (col=lane&15, row=4*(lane>>4)+reg) is HW-verified.
// H goes through a per-wave LDS tile [i][y] (stride 20 f16 = 40 B), written
// as D comes out, read back as B-operand rows (two 8B reads). Wave-private
// -> wave-synchronous, no barriers. Filter subtraction: stage2 accumulates
// with T_B negated. No bounds checks anywhere (fully padded image).
// One wave = one 16-col tile column, sweeping 32 y-tiles.
// ---------------------------------------------------------------------------
__global__ __launch_bounds__(256, 8)
void sinc_mfma(const _Float16* __restrict__ xh,
               const float* __restrict__ coefs,
               float* __restrict__ out) {
    __shared__ _Float16 cft[2][48];                       // Toeplitz tables
    __shared__ __align__(16) _Float16 hbuf[4][4][16][20]; // [wv][f*2+par][i][y]

    const int tid  = threadIdx.x;
    const int lane = tid & 63;
    const int wv   = tid >> 6;
    const int bid  = blockIdx.x;
    const int ch   = bid & 63;                 // channel fastest (L2 sharing)
    const int tcg  = (bid >> 6) & 7;
    const int b    = bid >> 9;
    const int c0   = (tcg * 4 + wv) * 16;      // tile column base

    // extended coef tables: cft[f][16+d] = cf_f[d], d in [0,15); zeros around
    if (tid < 96) {
        int f = tid / 48, d = tid % 48;
        float cv = (d >= 16 && d < 31) ? coefs[ch * 32 + f * 16 + (d - 16)]
                                       : 0.0f;
        cft[f][d] = (_Float16)cv;
    }
    __syncthreads();

    // build A-operand Toeplitz fragments: elem j of lane l -> k = 8*(l>>4)+j
    const int i16 = lane & 15;
    const int kb  = (lane >> 4) * 8;
    half8 TA, TB1, TB2;
    #pragma unroll
    for (int j = 0; j < 8; ++j) {
        int idx = 16 + kb + j - i16;           // in [1,47]
        TA[j]  = cft[0][idx];
        TB1[j] = cft[1][idx];
    }
    TB2 = -TB1;                                // folds the A-B subtraction

    // X fragment source: col index (c0 + k - 7) + 7 = c0 + k ; k = kb + j
    const _Float16* xb = xh + (size_t)b * YROWS * XROW + c0 + kb;

    const f32x4 zero = {0.f, 0.f, 0.f, 0.f};
    const int   i0   = (lane >> 4) * 4;        // D row base
    const int   gq   = lane >> 4;
    const int   klo  = (gq & 1) * 8;           // y-local base within H tile
    float* ob = out + ((size_t)(b * C_ + ch) * HW_) * (size_t)HW_ + c0 + i16;

    // ---- stage 1: compute H batch m, store to LDS parity m&1 ----
    auto stage1 = [&](int m) {
        // B1: lane holds rows y = 16m-7 + i16 (padded row 16m + i16),
        //     8 consecutive k -> 16 contiguous bytes
        half8 X = *(const half8*)(xb + (size_t)(16 * m + i16) * XROW);
        f32x4 hA = __builtin_amdgcn_mfma_f32_16x16x32_f16(TA,  X, zero, 0, 0, 0);
        f32x4 hB = __builtin_amdgcn_mfma_f32_16x16x32_f16(TB1, X, zero, 0, 0, 0);
        const int p = m & 1;
        #pragma unroll
        for (int mm = 0; mm < 4; ++mm) {       // D: row i = i0+mm, col y = i16
            hbuf[wv][p][i0 + mm][i16]     = (_Float16)hA[mm];
            hbuf[wv][2 + p][i0 + mm][i16] = (_Float16)hB[mm];
        }
    };

    // ---- stage 2: output tile t from H batches {t, t+1} ----
    auto stage2 = [&](int t) {
        // B2: lane group 0,1 -> batch t; 2,3 -> batch t+1; col n = i16
        const int p = (t + (gq >> 1)) & 1;
        const _Float16* ra = &hbuf[wv][p][i16][klo];
        const _Float16* rb = &hbuf[wv][2 + p][i16][klo];
        half4 la0 = *(const half4*)ra,       la1 = *(const half4*)(ra + 4);
        half4 lb0 = *(const half4*)rb,       lb1 = *(const half4*)(rb + 4);
        half8 HA = {la0[0], la0[1], la0[2], la0[3], la1[0], la1[1], la1[2], la1[3]};
        half8 HB = {lb0[0], lb0[1], lb0[2], lb0[3], lb1[0], lb1[1], lb1[2], lb1[3]};
        f32x4 O = __builtin_amdgcn_mfma_f32_16x16x32_f16(TA,  HA, zero, 0, 0, 0);
        O       = __builtin_amdgcn_mfma_f32_16x16x32_f16(TB2, HB, O,    0, 0, 0);
        const int r0 = 16 * t + i0;            // D: row y' = r0+mm, col x
        #pragma unroll
        for (int mm = 0; mm < 4; ++mm)
            __builtin_nontemporal_store(O[mm], ob + (size_t)(r0 + mm) * HW_);
    };

    stage1(0);
    #pragma unroll 2
    for (int t = 0; t < 32; ++t) {
        stage1(t + 1);                         // writes parity (t+1)&1
        stage2(t);                             // reads parities t&1,(t+1)&1
    }
}

extern "C" void kernel_launch(void* const* d_in, const int* in_sizes, int n_in,
                              void* d_out, int out_size, void* d_ws, size_t ws_size,
                              hipStream_t stream) {
    const float* x    = (const float*)d_in[0];
    const float* f1   = (const float*)d_in[1];
    const float* band = (const float*)d_in[2];
    float* ws   = (float*)d_ws;
    float* outp = (float*)d_out;
    _Float16* xh = (_Float16*)(ws + PADOFF);

    hipLaunchKernelGGL(make_filters, dim3(1), dim3(64), 0, stream,
                       f1, band, ws);

    int npad = (B_ * YROWS * (XROW / 8) + 255) / 256;    // 2244
    hipLaunchKernelGGL(pad_f16, dim3(npad), dim3(256), 0, stream, x, xh);

    const int nblocks = B_ * C_ * 8;           // 8192 blocks x 4 waves
    hipLaunchKernelGGL(sinc_mfma, dim3(nblocks), dim3(256), 0, stream,
                       xh, ws, outp);
}

// Round 18
// 209.060 us; speedup vs baseline: 2.2913x; 1.6149x over previous
//
#include <hip/hip_runtime.h>
#include <math.h>

#define B_     16
#define C_     64
#define HW_    512
#define KS_    15
#define XROW   544      // padded f16 row: col index = x + 7
#define YROWS  528      // padded rows per batch: row index = y + 7
#define PADOFF 2048     // floats reserved at ws start for fp32 coefs

typedef _Float16 half8 __attribute__((ext_vector_type(8)));
typedef _Float16 half4 __attribute__((ext_vector_type(4)));
typedef float    f32x4 __attribute__((ext_vector_type(4)));

// ---------------------------------------------------------------------------
// coefs[c*32 + i]      = F2*sinc(pi*F2*(i-7))*hamming[i]   (A)
// coefs[c*32 + 16 + i] = F1*sinc(pi*F1*(i-7))*hamming[i]   (B)
// ---------------------------------------------------------------------------
__global__ void make_filters(const float* __restrict__ f1,
                             const float* __restrict__ band,
                             float* __restrict__ coefs) {
    int c = threadIdx.x;
    if (c >= C_) return;
    float F1 = f1[c];
    float F2 = F1 + fabsf(band[c]);
    const float PI = 3.14159265358979323846f;
    #pragma unroll
    for (int i = 0; i < KS_; ++i) {
        float h = 0.54f - 0.46f * cosf((2.0f * PI / 14.0f) * (float)i);
        float y1, y2;
        if (i == 7) { y1 = 1.0f; y2 = 1.0f; }
        else {
            float t  = (float)(i - 7);
            float a1 = PI * F1 * t;
            float a2 = PI * F2 * t;
            y1 = sinf(a1) / a1;
            y2 = sinf(a2) / a2;
        }
        coefs[c * 32 + i]      = F2 * y2 * h;
        coefs[c * 32 + 16 + i] = F1 * y1 * h;
    }
}

// ---------------------------------------------------------------------------
// Fully padded f16 image: xh[b][y+7][x+7] = (f16)x[b][y][x], zero outside.
// ---------------------------------------------------------------------------
__global__ void pad_f16(const float* __restrict__ x, _Float16* __restrict__ xh) {
    int t = blockIdx.x * 256 + threadIdx.x;
    if (t >= B_ * YROWS * (XROW / 8)) return;
    int xq = t % (XROW / 8);
    int rr = t / (XROW / 8);
    int yy = rr % YROWS;
    int b  = rr / YROWS;
    int y  = yy - 7;
    half8 v = {0, 0, 0, 0, 0, 0, 0, 0};
    if ((unsigned)y < (unsigned)HW_) {
        const float* src = x + ((size_t)b * HW_ + y) * HW_;
        #pragma unroll
        for (int e = 0; e < 8; ++e) {
            int gx = 8 * xq + e - 7;
            if ((unsigned)gx < (unsigned)HW_) v[e] = (_Float16)src[gx];
        }
    }
    *(half8*)(xh + (size_t)rr * XROW + 8 * xq) = v;
}

// ---------------------------------------------------------------------------
// MFMA separable conv (R17-proven math) + block-cooperative store staging.
// Block = 512 threads = 8 waves covering 256 contiguous output cols; wave wv
// owns column-tiles at block_base + 32*wv + {0,16} (q=0,1). Per y-tile t:
//   stage1(q,t+1): H batch t+1 via mfma(T, X) -> per-wave hbuf (LDS)
//   stage2(q,t):   O tile via mfma(T, Hwin) -> fragments into shared obuf
//   barrier; store pass: each wave stores 2 FULL 256-float rows as ONE
//   dwordx4 instruction = 1 KB contiguous nontemporal (R8-proven clean
//   pattern; R17's 4x64B scatter is the R3/R4-proven ~2.6x write inflator);
//   barrier.
// A/B fragments share the (lanegroup,elem)->k map (k-order invariant);
// C/D layout col=lane&15, row=4*(lane>>4)+reg is HW-verified.
// ---------------------------------------------------------------------------
__global__ __launch_bounds__(512, 4)
void sinc_mfma2(const _Float16* __restrict__ xh,
                const float* __restrict__ coefs,
                float* __restrict__ out) {
    __shared__ _Float16 cft[2][48];
    __shared__ __align__(16) _Float16 hbuf[8][2][2][2][16][20]; // [wv][q][f][p][i][y]
    __shared__ __align__(16) float obuf[16][260];

    const int tid  = threadIdx.x;
    const int lane = tid & 63;
    const int wv   = tid >> 6;                 // 0..7
    const int bid  = blockIdx.x;
    const int ch   = bid & 63;                 // channel fastest (L2 sharing)
    const int cb   = (bid >> 6) & 1;           // column half (256 cols)
    const int b    = bid >> 7;

    // extended coef tables: cft[f][16+d] = cf_f[d], d in [0,15); zeros around
    if (tid < 96) {
        int f = tid / 48, d = tid % 48;
        float cv = (d >= 16 && d < 31) ? coefs[ch * 32 + f * 16 + (d - 16)]
                                       : 0.0f;
        cft[f][d] = (_Float16)cv;
    }
    __syncthreads();

    const int i16 = lane & 15;
    const int gq  = lane >> 4;
    const int kb  = gq * 8;
    half8 TA, TB1, TB2;
    #pragma unroll
    for (int j = 0; j < 8; ++j) {
        int idx = 16 + kb + j - i16;           // in [1,47]
        TA[j]  = cft[0][idx];
        TB1[j] = cft[1][idx];
    }
    TB2 = -TB1;                                // folds the A-B subtraction

    const f32x4 zero = {0.f, 0.f, 0.f, 0.f};
    const int   i0   = gq * 4;                 // D row base
    const int   klo  = (gq & 1) * 8;           // y-local base within H tile

    // X source for tile q: padded col (c0_q + k), c0_q = 256*cb + 32*wv + 16q
    const _Float16* xb0 = xh + (size_t)b * YROWS * XROW
                        + (256 * cb + 32 * wv) + kb;
    float* obase = out + ((size_t)(b * C_ + ch) * HW_) * (size_t)HW_
                 + 256 * cb;

    // ---- stage 1: H batch m of tile q -> LDS parity m&1 ----
    auto stage1 = [&](int q, int m) {
        half8 X = *(const half8*)(xb0 + 16 * q + (size_t)(16 * m + i16) * XROW);
        f32x4 hA = __builtin_amdgcn_mfma_f32_16x16x32_f16(TA,  X, zero, 0, 0, 0);
        f32x4 hB = __builtin_amdgcn_mfma_f32_16x16x32_f16(TB1, X, zero, 0, 0, 0);
        const int p = m & 1;
        #pragma unroll
        for (int mm = 0; mm < 4; ++mm) {       // D: row i = i0+mm, col y = i16
            hbuf[wv][q][0][p][i0 + mm][i16] = (_Float16)hA[mm];
            hbuf[wv][q][1][p][i0 + mm][i16] = (_Float16)hB[mm];
        }
    };

    // ---- stage 2: output tile t of tile-col q -> obuf fragments ----
    auto stage2 = [&](int q, int t) {
        const int p = (t + (gq >> 1)) & 1;     // groups 0,1 -> batch t; 2,3 -> t+1
        const _Float16* ra = &hbuf[wv][q][0][p][i16][klo];
        const _Float16* rb = &hbuf[wv][q][1][p][i16][klo];
        half4 la0 = *(const half4*)ra,  la1 = *(const half4*)(ra + 4);
        half4 lb0 = *(const half4*)rb,  lb1 = *(const half4*)(rb + 4);
        half8 HA = {la0[0], la0[1], la0[2], la0[3], la1[0], la1[1], la1[2], la1[3]};
        half8 HB = {lb0[0], lb0[1], lb0[2], lb0[3], lb1[0], lb1[1], lb1[2], lb1[3]};
        f32x4 O = __builtin_amdgcn_mfma_f32_16x16x32_f16(TA,  HA, zero, 0, 0, 0);
        O       = __builtin_amdgcn_mfma_f32_16x16x32_f16(TB2, HB, O,    0, 0, 0);
        const int col = 32 * wv + 16 * q + i16;
        #pragma unroll
        for (int mm = 0; mm < 4; ++mm)
            obuf[i0 + mm][col] = O[mm];
    };

    stage1(0, 0);
    stage1(1, 0);

    #pragma unroll 1
    for (int t = 0; t < 32; ++t) {
        stage1(0, t + 1);
        stage1(1, t + 1);
        stage2(0, t);
        stage2(1, t);
        __syncthreads();
        // store pass: wave wv -> rows {2wv, 2wv+1}; one 1KB contiguous
        // nontemporal dwordx4 instruction per row (R8-proven clean pattern)
        #pragma unroll
        for (int s = 0; s < 2; ++s) {
            const int r = 2 * wv + s;
            f32x4 v = *(const f32x4*)&obuf[r][4 * lane];
            __builtin_nontemporal_store(v,
                (f32x4*)(obase + (size_t)(16 * t + r) * HW_ + 4 * lane));
        }
        __syncthreads();
    }
}

extern "C" void kernel_launch(void* const* d_in, const int* in_sizes, int n_in,
                              void* d_out, int out_size, void* d_ws, size_t ws_size,
                              hipStream_t stream) {
    const float* x    = (const float*)d_in[0];
    const float* f1   = (const float*)d_in[1];
    const float* band = (const float*)d_in[2];
    float* ws   = (float*)d_ws;
    float* outp = (float*)d_out;
    _Float16* xh = (_Float16*)(ws + PADOFF);

    hipLaunchKernelGGL(make_filters, dim3(1), dim3(64), 0, stream,
                       f1, band, ws);

    int npad = (B_ * YROWS * (XROW / 8) + 255) / 256;    // 2244
    hipLaunchKernelGGL(pad_f16, dim3(npad), dim3(256), 0, stream, x, xh);

    const int nblocks = B_ * C_ * 2;           // 2048 blocks x 8 waves
    hipLaunchKernelGGL(sinc_mfma2, dim3(nblocks), dim3(512), 0, stream,
                       xh, ws, outp);
}

// Round 19
// 205.619 us; speedup vs baseline: 2.3296x; 1.0167x over previous
//
#include <hip/hip_runtime.h>
#include <math.h>

#define B_     16
#define C_     64
#define HW_    512
#define KS_    15
#define XROW   544      // padded f16 row: col index = x + 7
#define YROWS  528      // padded rows per batch: row index = y + 7
#define PADOFF 2048     // floats reserved at ws start for fp32 coefs

typedef _Float16 half8 __attribute__((ext_vector_type(8)));
typedef _Float16 half4 __attribute__((ext_vector_type(4)));
typedef float    f32x4 __attribute__((ext_vector_type(4)));

// ---------------------------------------------------------------------------
// coefs[c*32 + i]      = F2*sinc(pi*F2*(i-7))*hamming[i]   (A)
// coefs[c*32 + 16 + i] = F1*sinc(pi*F1*(i-7))*hamming[i]   (B)
// ---------------------------------------------------------------------------
__global__ void make_filters(const float* __restrict__ f1,
                             const float* __restrict__ band,
                             float* __restrict__ coefs) {
    int c = threadIdx.x;
    if (c >= C_) return;
    float F1 = f1[c];
    float F2 = F1 + fabsf(band[c]);
    const float PI = 3.14159265358979323846f;
    #pragma unroll
    for (int i = 0; i < KS_; ++i) {
        float h = 0.54f - 0.46f * cosf((2.0f * PI / 14.0f) * (float)i);
        float y1, y2;
        if (i == 7) { y1 = 1.0f; y2 = 1.0f; }
        else {
            float t  = (float)(i - 7);
            float a1 = PI * F1 * t;
            float a2 = PI * F2 * t;
            y1 = sinf(a1) / a1;
            y2 = sinf(a2) / a2;
        }
        coefs[c * 32 + i]      = F2 * y2 * h;
        coefs[c * 32 + 16 + i] = F1 * y1 * h;
    }
}

// ---------------------------------------------------------------------------
// Fully padded f16 image: xh[b][y+7][x+7] = (f16)x[b][y][x], zero outside.
// ---------------------------------------------------------------------------
__global__ void pad_f16(const float* __restrict__ x, _Float16* __restrict__ xh) {
    int t = blockIdx.x * 256 + threadIdx.x;
    if (t >= B_ * YROWS * (XROW / 8)) return;
    int xq = t % (XROW / 8);
    int rr = t / (XROW / 8);
    int yy = rr % YROWS;
    int b  = rr / YROWS;
    int y  = yy - 7;
    half8 v = {0, 0, 0, 0, 0, 0, 0, 0};
    if ((unsigned)y < (unsigned)HW_) {
        const float* src = x + ((size_t)b * HW_ + y) * HW_;
        #pragma unroll
        for (int e = 0; e < 8; ++e) {
            int gx = 8 * xq + e - 7;
            if ((unsigned)gx < (unsigned)HW_) v[e] = (_Float16)src[gx];
        }
    }
    *(half8*)(xh + (size_t)rr * XROW + 8 * xq) = v;
}

// ---------------------------------------------------------------------------
// MFMA separable conv (R17/R18-proven math + store staging) with DOUBLE-
// BUFFERED obuf: one barrier per y-tile instead of two. stage2(t) writes
// obuf[t&1]; barrier; store pass reads obuf[t&1] while the next iteration's
// stage2 writes obuf[(t+1)&1]. Reclaim of obuf[t&1] (tile t+2's stage2)
// sits behind tile t+1's barrier, which every wave passes only after
// finishing its tile-t stores -> race-free with 32 barriers.
// Store pass: each wave stores 2 full 256-float rows as ONE dwordx4
// instruction = 1 KB contiguous nontemporal (the R18-proven clean pattern).
// ---------------------------------------------------------------------------
__global__ __launch_bounds__(512, 4)
void sinc_mfma3(const _Float16* __restrict__ xh,
                const float* __restrict__ coefs,
                float* __restrict__ out) {
    __shared__ _Float16 cft[2][48];
    __shared__ __align__(16) _Float16 hbuf[8][2][2][2][16][20]; // [wv][q][f][p][i][y]
    __shared__ __align__(16) float obuf[2][16][260];

    const int tid  = threadIdx.x;
    const int lane = tid & 63;
    const int wv   = tid >> 6;                 // 0..7
    const int bid  = blockIdx.x;
    const int ch   = bid & 63;                 // channel fastest (L2 sharing)
    const int cb   = (bid >> 6) & 1;           // column half (256 cols)
    const int b    = bid >> 7;

    // extended coef tables: cft[f][16+d] = cf_f[d], d in [0,15); zeros around
    if (tid < 96) {
        int f = tid / 48, d = tid % 48;
        float cv = (d >= 16 && d < 31) ? coefs[ch * 32 + f * 16 + (d - 16)]
                                       : 0.0f;
        cft[f][d] = (_Float16)cv;
    }
    __syncthreads();

    const int i16 = lane & 15;
    const int gq  = lane >> 4;
    const int kb  = gq * 8;
    half8 TA, TB1, TB2;
    #pragma unroll
    for (int j = 0; j < 8; ++j) {
        int idx = 16 + kb + j - i16;           // in [1,47]
        TA[j]  = cft[0][idx];
        TB1[j] = cft[1][idx];
    }
    TB2 = -TB1;                                // folds the A-B subtraction

    const f32x4 zero = {0.f, 0.f, 0.f, 0.f};
    const int   i0   = gq * 4;                 // D row base
    const int   klo  = (gq & 1) * 8;           // y-local base within H tile

    // X source for tile q: padded col (c0_q + k), c0_q = 256*cb + 32*wv + 16q
    const _Float16* xb0 = xh + (size_t)b * YROWS * XROW
                        + (256 * cb + 32 * wv) + kb;
    float* obase = out + ((size_t)(b * C_ + ch) * HW_) * (size_t)HW_
                 + 256 * cb;

    // ---- stage 1: H batch m of tile q -> LDS parity m&1 ----
    auto stage1 = [&](int q, int m) {
        half8 X = *(const half8*)(xb0 + 16 * q + (size_t)(16 * m + i16) * XROW);
        f32x4 hA = __builtin_amdgcn_mfma_f32_16x16x32_f16(TA,  X, zero, 0, 0, 0);
        f32x4 hB = __builtin_amdgcn_mfma_f32_16x16x32_f16(TB1, X, zero, 0, 0, 0);
        const int p = m & 1;
        #pragma unroll
        for (int mm = 0; mm < 4; ++mm) {       // D: row i = i0+mm, col y = i16
            hbuf[wv][q][0][p][i0 + mm][i16] = (_Float16)hA[mm];
            hbuf[wv][q][1][p][i0 + mm][i16] = (_Float16)hB[mm];
        }
    };

    // ---- stage 2: output tile t of tile-col q -> obuf[t&1] fragments ----
    auto stage2 = [&](int q, int t) {
        const int p = (t + (gq >> 1)) & 1;     // groups 0,1 -> batch t; 2,3 -> t+1
        const _Float16* ra = &hbuf[wv][q][0][p][i16][klo];
        const _Float16* rb = &hbuf[wv][q][1][p][i16][klo];
        half4 la0 = *(const half4*)ra,  la1 = *(const half4*)(ra + 4);
        half4 lb0 = *(const half4*)rb,  lb1 = *(const half4*)(rb + 4);
        half8 HA = {la0[0], la0[1], la0[2], la0[3], la1[0], la1[1], la1[2], la1[3]};
        half8 HB = {lb0[0], lb0[1], lb0[2], lb0[3], lb1[0], lb1[1], lb1[2], lb1[3]};
        f32x4 O = __builtin_amdgcn_mfma_f32_16x16x32_f16(TA,  HA, zero, 0, 0, 0);
        O       = __builtin_amdgcn_mfma_f32_16x16x32_f16(TB2, HB, O,    0, 0, 0);
        const int col = 32 * wv + 16 * q + i16;
        #pragma unroll
        for (int mm = 0; mm < 4; ++mm)
            obuf[t & 1][i0 + mm][col] = O[mm];
    };

    stage1(0, 0);
    stage1(1, 0);

    #pragma unroll 1
    for (int t = 0; t < 32; ++t) {
        stage1(0, t + 1);
        stage1(1, t + 1);
        stage2(0, t);
        stage2(1, t);
        __syncthreads();                       // stage2(t) done -> store t
        #pragma unroll
        for (int s = 0; s < 2; ++s) {
            const int r = 2 * wv + s;
            f32x4 v = *(const f32x4*)&obuf[t & 1][r][4 * lane];
            __builtin_nontemporal_store(v,
                (f32x4*)(obase + (size_t)(16 * t + r) * HW_ + 4 * lane));
        }
        // no trailing barrier: next stage2 writes obuf[(t+1)&1]; obuf[t&1]
        // is reclaimed only at t+2, behind the t+1 barrier.
    }
}

extern "C" void kernel_launch(void* const* d_in, const int* in_sizes, int n_in,
                              void* d_out, int out_size, void* d_ws, size_t ws_size,
                              hipStream_t stream) {
    const float* x    = (const float*)d_in[0];
    const float* f1   = (const float*)d_in[1];
    const float* band = (const float*)d_in[2];
    float* ws   = (float*)d_ws;
    float* outp = (float*)d_out;
    _Float16* xh = (_Float16*)(ws + PADOFF);

    hipLaunchKernelGGL(make_filters, dim3(1), dim3(64), 0, stream,
                       f1, band, ws);

    int npad = (B_ * YROWS * (XROW / 8) + 255) / 256;    // 2244
    hipLaunchKernelGGL(pad_f16, dim3(npad), dim3(256), 0, stream, x, xh);

    const int nblocks = B_ * C_ * 2;           // 2048 blocks x 8 waves
    hipLaunchKernelGGL(sinc_mfma3, dim3(nblocks), dim3(512), 0, stream,
                       xh, ws, outp);
}

// Round 20
// 203.415 us; speedup vs baseline: 2.3549x; 1.0108x over previous
//
#include <hip/hip_runtime.h>
#include <math.h>

#define B_     16
#define C_     64
#define HW_    512
#define KS_    15
#define XROW   544      // padded f16 row: col index = x + 7
#define YROWS  528      // padded rows per batch: row index = y + 7
#define PADOFF 2048     // floats reserved at ws start for fp32 coefs

typedef _Float16 half8 __attribute__((ext_vector_type(8)));
typedef _Float16 half4 __attribute__((ext_vector_type(4)));
typedef float    f32x4 __attribute__((ext_vector_type(4)));

// ---------------------------------------------------------------------------
// Fused prelude: pads the f16 image AND (block 0, lanes 0..63) computes the
// filter coefficient table:
//   coefs[c*32 + i]      = F2*sinc(pi*F2*(i-7))*hamming[i]   (A)
//   coefs[c*32 + 16 + i] = F1*sinc(pi*F1*(i-7))*hamming[i]   (B)
// pad_f16 itself never reads coefs -> no intra-grid ordering hazard; the
// main kernel (next launch) sees both results.
// ---------------------------------------------------------------------------
__global__ void pad_f16(const float* __restrict__ x, _Float16* __restrict__ xh,
                        const float* __restrict__ f1,
                        const float* __restrict__ band,
                        float* __restrict__ coefs) {
    if (blockIdx.x == 0 && threadIdx.x < C_) {
        int c = threadIdx.x;
        float F1 = f1[c];
        float F2 = F1 + fabsf(band[c]);
        const float PI = 3.14159265358979323846f;
        #pragma unroll
        for (int i = 0; i < KS_; ++i) {
            float h = 0.54f - 0.46f * cosf((2.0f * PI / 14.0f) * (float)i);
            float y1, y2;
            if (i == 7) { y1 = 1.0f; y2 = 1.0f; }
            else {
                float t  = (float)(i - 7);
                float a1 = PI * F1 * t;
                float a2 = PI * F2 * t;
                y1 = sinf(a1) / a1;
                y2 = sinf(a2) / a2;
            }
            coefs[c * 32 + i]      = F2 * y2 * h;
            coefs[c * 32 + 16 + i] = F1 * y1 * h;
        }
    }
    int t = blockIdx.x * 256 + threadIdx.x;
    if (t >= B_ * YROWS * (XROW / 8)) return;
    int xq = t % (XROW / 8);
    int rr = t / (XROW / 8);
    int yy = rr % YROWS;
    int b  = rr / YROWS;
    int y  = yy - 7;
    half8 v = {0, 0, 0, 0, 0, 0, 0, 0};
    if ((unsigned)y < (unsigned)HW_) {
        const float* src = x + ((size_t)b * HW_ + y) * HW_;
        #pragma unroll
        for (int e = 0; e < 8; ++e) {
            int gx = 8 * xq + e - 7;
            if ((unsigned)gx < (unsigned)HW_) v[e] = (_Float16)src[gx];
        }
    }
    *(half8*)(xh + (size_t)rr * XROW + 8 * xq) = v;
}

// ---------------------------------------------------------------------------
// MFMA separable conv (R19-proven: Toeplitz mfma stages, per-wave hbuf,
// double-buffered obuf with one barrier/tile, 1KB-contiguous NT stores).
// ONE change: OUTPUT-ADDRESS-ORDERED GRID. bid = ((b*64+ch)*2+cb) so
// consecutive (and hence concurrently-resident) blocks write consecutive
// output regions -> DRAM row-buffer locality matches the 6.5 TB/s memset
// pattern instead of scattering 1KB chunks across the whole 1 GB output.
// (Input locality is unaffected: the 9.2 MB f16 image is L3-resident.)
// ---------------------------------------------------------------------------
__global__ __launch_bounds__(512, 4)
void sinc_mfma4(const _Float16* __restrict__ xh,
                const float* __restrict__ coefs,
                float* __restrict__ out) {
    __shared__ _Float16 cft[2][48];
    __shared__ __align__(16) _Float16 hbuf[8][2][2][2][16][20]; // [wv][q][f][p][i][y]
    __shared__ __align__(16) float obuf[2][16][260];

    const int tid  = threadIdx.x;
    const int lane = tid & 63;
    const int wv   = tid >> 6;                 // 0..7
    const int bid  = blockIdx.x;
    const int cb   = bid & 1;                  // column half (256 cols) fastest
    const int ch   = (bid >> 1) & 63;
    const int b    = bid >> 7;

    // extended coef tables: cft[f][16+d] = cf_f[d], d in [0,15); zeros around
    if (tid < 96) {
        int f = tid / 48, d = tid % 48;
        float cv = (d >= 16 && d < 31) ? coefs[ch * 32 + f * 16 + (d - 16)]
                                       : 0.0f;
        cft[f][d] = (_Float16)cv;
    }
    __syncthreads();

    const int i16 = lane & 15;
    const int gq  = lane >> 4;
    const int kb  = gq * 8;
    half8 TA, TB1, TB2;
    #pragma unroll
    for (int j = 0; j < 8; ++j) {
        int idx = 16 + kb + j - i16;           // in [1,47]
        TA[j]  = cft[0][idx];
        TB1[j] = cft[1][idx];
    }
    TB2 = -TB1;                                // folds the A-B subtraction

    const f32x4 zero = {0.f, 0.f, 0.f, 0.f};
    const int   i0   = gq * 4;                 // D row base
    const int   klo  = (gq & 1) * 8;           // y-local base within H tile

    // X source for tile q: padded col (c0_q + k), c0_q = 256*cb + 32*wv + 16q
    const _Float16* xb0 = xh + (size_t)b * YROWS * XROW
                        + (256 * cb + 32 * wv) + kb;
    float* obase = out + ((size_t)(b * C_ + ch) * HW_) * (size_t)HW_
                 + 256 * cb;

    // ---- stage 1: H batch m of tile q -> LDS parity m&1 ----
    auto stage1 = [&](int q, int m) {
        half8 X = *(const half8*)(xb0 + 16 * q + (size_t)(16 * m + i16) * XROW);
        f32x4 hA = __builtin_amdgcn_mfma_f32_16x16x32_f16(TA,  X, zero, 0, 0, 0);
        f32x4 hB = __builtin_amdgcn_mfma_f32_16x16x32_f16(TB1, X, zero, 0, 0, 0);
        const int p = m & 1;
        #pragma unroll
        for (int mm = 0; mm < 4; ++mm) {       // D: row i = i0+mm, col y = i16
            hbuf[wv][q][0][p][i0 + mm][i16] = (_Float16)hA[mm];
            hbuf[wv][q][1][p][i0 + mm][i16] = (_Float16)hB[mm];
        }
    };

    // ---- stage 2: output tile t of tile-col q -> obuf[t&1] fragments ----
    auto stage2 = [&](int q, int t) {
        const int p = (t + (gq >> 1)) & 1;     // groups 0,1 -> batch t; 2,3 -> t+1
        const _Float16* ra = &hbuf[wv][q][0][p][i16][klo];
        const _Float16* rb = &hbuf[wv][q][1][p][i16][klo];
        half4 la0 = *(const half4*)ra,  la1 = *(const half4*)(ra + 4);
        half4 lb0 = *(const half4*)rb,  lb1 = *(const half4*)(rb + 4);
        half8 HA = {la0[0], la0[1], la0[2], la0[3], la1[0], la1[1], la1[2], la1[3]};
        half8 HB = {lb0[0], lb0[1], lb0[2], lb0[3], lb1[0], lb1[1], lb1[2], lb1[3]};
        f32x4 O = __builtin_amdgcn_mfma_f32_16x16x32_f16(TA,  HA, zero, 0, 0, 0);
        O       = __builtin_amdgcn_mfma_f32_16x16x32_f16(TB2, HB, O,    0, 0, 0);
        const int col = 32 * wv + 16 * q + i16;
        #pragma unroll
        for (int mm = 0; mm < 4; ++mm)
            obuf[t & 1][i0 + mm][col] = O[mm];
    };

    stage1(0, 0);
    stage1(1, 0);

    #pragma unroll 1
    for (int t = 0; t < 32; ++t) {
        stage1(0, t + 1);
        stage1(1, t + 1);
        stage2(0, t);
        stage2(1, t);
        __syncthreads();                       // stage2(t) done -> store t
        #pragma unroll
        for (int s = 0; s < 2; ++s) {
            const int r = 2 * wv + s;
            f32x4 v = *(const f32x4*)&obuf[t & 1][r][4 * lane];
            __builtin_nontemporal_store(v,
                (f32x4*)(obase + (size_t)(16 * t + r) * HW_ + 4 * lane));
        }
        // no trailing barrier: next stage2 writes obuf[(t+1)&1]; obuf[t&1]
        // is reclaimed only at t+2, behind the t+1 barrier.
    }
}

extern "C" void kernel_launch(void* const* d_in, const int* in_sizes, int n_in,
                              void* d_out, int out_size, void* d_ws, size_t ws_size,
                              hipStream_t stream) {
    const float* x    = (const float*)d_in[0];
    const float* f1   = (const float*)d_in[1];
    const float* band = (const float*)d_in[2];
    float* ws   = (float*)d_ws;
    float* outp = (float*)d_out;
    _Float16* xh = (_Float16*)(ws + PADOFF);

    int npad = (B_ * YROWS * (XROW / 8) + 255) / 256;    // 2244
    hipLaunchKernelGGL(pad_f16, dim3(npad), dim3(256), 0, stream,
                       x, xh, f1, band, ws);

    const int nblocks = B_ * C_ * 2;           // 2048 blocks x 8 waves
    hipLaunchKernelGGL(sinc_mfma4, dim3(nblocks), dim3(512), 0, stream,
                       xh, ws, outp);
}